// Round 7
// baseline (1331.034 us; speedup 1.0000x reference)
//
#include <hip/hip_runtime.h>
#include <math.h>

// Problem dims: B=4, T=128, I=32, H=64 (compile-time)
// d_out float layout (reference return order):
// final_carry (4,64) | out (4,128,64) | J_Wi (4,128,64,32,64) | J_Wh (4,128,64,64,64)
// | J_b (4,128,64,64) | J_h (4,128,64,4,64)
#define OFF_OUT   256u
#define OFF_JWI   33024u
#define OFF_JWH   67141888u
#define OFF_JB    201359616u
#define OFF_JH    203456768u
#define OUT_TOTAL 211845376u

typedef float f32x4 __attribute__((ext_vector_type(4)));

static __device__ __forceinline__ float tanh_fast(float x) {
    // tanh(x) = 1 - 2/(e^{2x}+1); exact limits, ~1e-6 rel error
    float t = __expf(2.0f * x);
    return 1.0f - 2.0f / (t + 1.0f);
}

// ---------------------------------------------------------------------------
// Kernel 1: u[bt,j] = b[j] + sum_i x[bt,i]*Wi[i,j], staged INTO the `out`
// region (scan consumes it and overwrites with a). Also clears the 64
// progress flags in d_ws (kernel boundary makes this visible device-wide).
// ---------------------------------------------------------------------------
__global__ __launch_bounds__(256) void xwi_kernel(
    const float* __restrict__ x, const float* __restrict__ Wi,
    const float* __restrict__ bias, float* __restrict__ out,
    int* __restrict__ flags)
{
    const int tid = threadIdx.x;
    if (blockIdx.x == 0 && tid < 64) flags[tid] = 0;
    const int row = blockIdx.x * 4 + (tid >> 6);   // bt in [0,512)
    const int j = tid & 63;
    const float* xr = x + row * 32;
    float acc = bias[j];
#pragma unroll
    for (int i = 0; i < 32; ++i) acc = fmaf(xr[i], Wi[i * 64 + j], acc);
    out[OFF_OUT + row * 64 + j] = acc;
}

// ---------------------------------------------------------------------------
// Kernel 2 (mega): block 0 = sequential scan (wave w = batch w, barrier-free,
// depth-2 global u prefetch). Publishes flags[b*16+tg]=1 after storing steps
// tg*8..tg*8+7 (threadfence + agent-scope release store).
// Blocks 1..3232 = dense single-touch full-line fill; each block acquire-polls
// the one flag covering the newest scan value it reads, then streams its slab.
//   blk [0,2048):     J_Wh  (bt = blk>>2, j-quarter)   256KB each
//   blk [2048,3072):  J_Wi  (bt = idx>>1, j-half)      256KB each
//   blk [3072,3104):  J_b   (c: rows [c*1024,+1024))   256KB each
//   blk [3104,3232):  J_h   (q: 4 bt-slabs each)       64KB each
// ---------------------------------------------------------------------------
__global__ __launch_bounds__(256) void mega_kernel(
    const float* __restrict__ carry, const float* __restrict__ x,
    const float* __restrict__ Wh, float* __restrict__ out,
    int* __restrict__ flags)
{
    __shared__ float smem[4608];                   // 18 KB, carved per role
    const int tid = threadIdx.x;
    const float* __restrict__ outh = out + OFF_OUT;

    if (blockIdx.x == 0) {
        // ---------------- scan ----------------
        const int w = tid >> 6, j = tid & 63;      // wave w = batch w
        float wcol[64];
#pragma unroll
        for (int m = 0; m < 64; ++m) wcol[m] = Wh[m * 64 + j];
        float* sh = smem;                          // 256 floats
        sh[tid] = carry[tid];
        float* ub = out + OFF_OUT + w * 8192;      // u in, a out (in place)
        float u0 = ub[j];                          // t
        float u1 = ub[64 + j];                     // t+1 (depth-2 prefetch)
        const f32x4* shv = reinterpret_cast<const f32x4*>(sh + w * 64);
        float a = 0.0f;
        for (int tg = 0; tg < 16; ++tg) {
#pragma unroll
            for (int ts = 0; ts < 8; ++ts) {
                const int t = tg * 8 + ts;
                const float pre = u0;
                u0 = u1;
                if (t + 2 < 128) u1 = ub[(t + 2) * 64 + j];
                float s0 = 0.f, s1 = 0.f, s2 = 0.f, s3 = 0.f;
#pragma unroll
                for (int mm = 0; mm < 16; ++mm) {
                    const f32x4 hv = shv[mm];      // lane-uniform broadcast
                    s0 = fmaf(hv.x, wcol[mm * 4 + 0], s0);
                    s1 = fmaf(hv.y, wcol[mm * 4 + 1], s1);
                    s2 = fmaf(hv.z, wcol[mm * 4 + 2], s2);
                    s3 = fmaf(hv.w, wcol[mm * 4 + 3], s3);
                }
                a = tanh_fast(pre + (s0 + s1) + (s2 + s3));
                ub[t * 64 + j] = a;                // global store (a)
                sh[tid] = a;                       // same-wave LDS exchange
            }
            __threadfence();                       // drain a-stores device-wide
            if (j == 0)
                __hip_atomic_store(&flags[w * 16 + tg], 1,
                                   __ATOMIC_RELEASE, __HIP_MEMORY_SCOPE_AGENT);
        }
        out[tid] = a;                              // final carry
        return;
    }

    // ---------------- fill ----------------
    const unsigned blk = blockIdx.x - 1u;
    const unsigned rowq = tid >> 4;                // 16-lane group id [0,16)
    const unsigned k0 = (tid & 15u) * 4;           // k offset of lane's float4

    // flag index this block must wait on (wave-uniform per block)
    unsigned fidx;
    if (blk < 2048u) {
        const unsigned bt = blk >> 2;
        fidx = (bt >> 7) * 16u + ((bt & 127u) >> 3);
    } else if (blk < 3072u) {
        const unsigned bt = (blk - 2048u) >> 1;
        fidx = (bt >> 7) * 16u + ((bt & 127u) >> 3);
    } else if (blk < 3104u) {
        const unsigned c = blk - 3072u;
        fidx = (c >> 3) * 16u + (c & 7u) * 2u + 1u;
    } else {
        const unsigned q = blk - 3104u;
        fidx = (q >> 5) * 16u + ((q & 31u) >> 1);
    }
    while (__hip_atomic_load(&flags[fidx], __ATOMIC_ACQUIRE,
                             __HIP_MEMORY_SCOPE_AGENT) == 0)
        __builtin_amdgcn_s_sleep(2);

    if (blk < 2048u) {
        // ---- J_Wh ----
        const unsigned bt = blk >> 2, jq = blk & 3u;
        const unsigned t = bt & 127u, bb = bt >> 7;
        if (tid < 16) {
            const float aa = outh[bt * 64 + jq * 16 + tid];
            smem[tid] = 1.0f - aa * aa;            // g[jloc]
        } else if (tid >= 64 && tid < 128) {
            const unsigned m = tid - 64;
            smem[64 + m] = (t == 0u) ? carry[bb * 64 + m]
                                     : outh[(bt - 1u) * 64 + m];
        }
        __syncthreads();
        f32x4* dst = reinterpret_cast<f32x4*>(
            out + (size_t)OFF_JWH + (size_t)bt * 262144 + jq * 65536);
        const unsigned jbase = jq * 16;
#pragma unroll 2
        for (int it = 0; it < 64; ++it) {
            const unsigned R = it * 16 + rowq;     // (jloc,m) row in [0,1024)
            const unsigned jloc = R >> 6, m = R & 63u;
            const float val = smem[jloc] * smem[64 + m];
            const unsigned d = (jbase + jloc) - k0;
            f32x4 r;
            r.x = (d == 0u) ? val : 0.f; r.y = (d == 1u) ? val : 0.f;
            r.z = (d == 2u) ? val : 0.f; r.w = (d == 3u) ? val : 0.f;
            __builtin_nontemporal_store(r, dst + it * 256 + tid);
        }
    } else if (blk < 3072u) {
        // ---- J_Wi ----
        const unsigned idx = blk - 2048u;
        const unsigned bt = idx >> 1, jh = idx & 1u;
        if (tid < 32) {
            const float aa = outh[bt * 64 + jh * 32 + tid];
            smem[tid] = 1.0f - aa * aa;            // g[jloc]
            smem[32 + tid] = x[bt * 32 + tid];     // x[i]
        }
        __syncthreads();
        f32x4* dst = reinterpret_cast<f32x4*>(
            out + (size_t)OFF_JWI + (size_t)bt * 131072 + jh * 65536);
        const unsigned jbase = jh * 32;
#pragma unroll 2
        for (int it = 0; it < 64; ++it) {
            const unsigned R = it * 16 + rowq;     // (jloc,i) row in [0,1024)
            const unsigned jloc = R >> 5, i = R & 31u;
            const float val = smem[jloc] * smem[32 + i];
            const unsigned d = (jbase + jloc) - k0;
            f32x4 r;
            r.x = (d == 0u) ? val : 0.f; r.y = (d == 1u) ? val : 0.f;
            r.z = (d == 2u) ? val : 0.f; r.w = (d == 3u) ? val : 0.f;
            __builtin_nontemporal_store(r, dst + it * 256 + tid);
        }
    } else if (blk < 3104u) {
        // ---- J_b ----
        const unsigned c = blk - 3072u;
        for (int p = tid; p < 1024; p += 256) {
            const float aa = outh[c * 1024 + p];
            smem[p] = 1.0f - aa * aa;
        }
        __syncthreads();
        f32x4* dst = reinterpret_cast<f32x4*>(
            out + (size_t)OFF_JB + (size_t)c * 65536);
#pragma unroll 2
        for (int it = 0; it < 64; ++it) {
            const unsigned R = it * 16 + rowq;     // local row
            const unsigned j = R & 63u;
            const float val = smem[R];
            const unsigned d = j - k0;
            f32x4 r;
            r.x = (d == 0u) ? val : 0.f; r.y = (d == 1u) ? val : 0.f;
            r.z = (d == 2u) ? val : 0.f; r.w = (d == 3u) ? val : 0.f;
            __builtin_nontemporal_store(r, dst + it * 256 + tid);
        }
    } else {
        // ---- J_h ---- (whT stride 68: 16B-aligned rows, low bank aliasing)
        const unsigned q = blk - 3104u;            // [0,128): 4 bt-slabs each
        float* whT = smem;                         // 64*68 floats
        float* sg = smem + 4352;                   // 256 floats
        for (int p = tid; p < 4096; p += 256) {
            const unsigned m = p >> 6, j = p & 63u;
            whT[j * 68 + m] = Wh[p];
        }
        {
            const unsigned s = tid >> 6, j = tid & 63u;
            const float aa = outh[(q * 4 + s) * 64 + j];
            sg[tid] = 1.0f - aa * aa;
        }
        __syncthreads();
        const unsigned m0 = (tid & 15u) * 4;
        f32x4* dst = reinterpret_cast<f32x4*>(
            out + (size_t)OFF_JH + (size_t)q * 65536);
#pragma unroll 2
        for (int it = 0; it < 64; ++it) {
            const unsigned R = it * 16 + rowq;     // row = s*256 + j*4 + c
            const unsigned s = R >> 8;
            const unsigned j = (R >> 2) & 63u;
            const unsigned cc = R & 3u;
            const unsigned bb = (q * 4 + s) >> 7;
            f32x4 r = {0.f, 0.f, 0.f, 0.f};
            if (cc == bb) {
                const float g = sg[s * 64 + j];
                const float* wrow = &whT[j * 68 + m0];
                r.x = g * wrow[0]; r.y = g * wrow[1];
                r.z = g * wrow[2]; r.w = g * wrow[3];
            }
            __builtin_nontemporal_store(r, dst + it * 256 + tid);
        }
    }
}

extern "C" void kernel_launch(void* const* d_in, const int* in_sizes, int n_in,
                              void* d_out, int out_size, void* d_ws, size_t ws_size,
                              hipStream_t stream) {
    const float* carry = (const float*)d_in[0];
    const float* x     = (const float*)d_in[1];
    const float* Wi    = (const float*)d_in[2];
    const float* Wh    = (const float*)d_in[3];
    const float* bias  = (const float*)d_in[4];
    float* out = (float*)d_out;
    int* flags = (int*)d_ws;                       // 64 ints of scratch

    xwi_kernel <<<128, 256, 0, stream>>>(x, Wi, bias, out, flags);
    mega_kernel<<<3233, 256, 0, stream>>>(carry, x, Wh, out, flags);
}

// Round 8
// 215.700 us; speedup vs baseline: 6.1708x; 6.1708x over previous
//
#include <hip/hip_runtime.h>
#include <math.h>

// Problem dims: B=4, T=128, I=32, H=64 (compile-time)
// d_out float layout (reference return order):
// final_carry (4,64) | out (4,128,64) | J_Wi (4,128,64,32,64) | J_Wh (4,128,64,64,64)
// | J_b (4,128,64,64) | J_h (4,128,64,4,64)
#define OFF_OUT   256u
#define OFF_JWI   33024u
#define OFF_JWH   67141888u
#define OFF_JB    201359616u
#define OFF_JH    203456768u
#define OUT_TOTAL 211845376u

// float4-unit boundaries (all 64-unit aligned -> wave-uniform region branches)
#define JWI4 8256u
#define JWH4 16785472u
#define JB4  50339904u
#define JH4  50864192u
#define END4 52961344u

typedef float f32x4 __attribute__((ext_vector_type(4)));

static __device__ __forceinline__ float tanh_fast(float x) {
    // tanh(x) = 1 - 2/(e^{2x}+1); exact limits, ~1e-6 rel error
    float t = __expf(2.0f * x);
    return 1.0f - 2.0f / (t + 1.0f);
}

// ---------------------------------------------------------------------------
// Kernel 0: WhT builder — whT[k*64+m] = Wh[m*64+k] (16 KB in d_ws).
// ---------------------------------------------------------------------------
__global__ __launch_bounds__(256) void whT_kernel(
    const float* __restrict__ Wh, float* __restrict__ whT)
{
    const int p = blockIdx.x * 256 + threadIdx.x;  // [0,4096)
    const int m = p >> 6, k = p & 63;
    whT[k * 64 + m] = Wh[p];
}

// ---------------------------------------------------------------------------
// Kernel 1: u[bt,j] = b[j] + sum_i x[bt,i]*Wi[i,j], staged INTO the `out`
// region (scan overwrites with a). 128 blocks x 256 threads.
// ---------------------------------------------------------------------------
__global__ __launch_bounds__(256) void xwi_kernel(
    const float* __restrict__ x, const float* __restrict__ Wi,
    const float* __restrict__ bias, float* __restrict__ out)
{
    const int tid = threadIdx.x;
    const int row = blockIdx.x * 4 + (tid >> 6);   // bt in [0,512)
    const int j = tid & 63;
    const float* xr = x + row * 32;
    float acc = bias[j];
#pragma unroll
    for (int i = 0; i < 32; ++i) acc = fmaf(xr[i], Wi[i * 64 + j], acc);
    out[OFF_OUT + row * 64 + j] = acc;
}

// ---------------------------------------------------------------------------
// Kernel 2: sequential scan. 4 blocks (1 wave each), block = batch.
// Depth-2 global u prefetch; Wh column j in 64 VGPRs; same-wave LDS h
// exchange (no barriers). Also materializes hprev[bt*64+m] = h entering
// step t into d_ws (kills the t==0/carry divergence in the J_Wh sweep).
// ---------------------------------------------------------------------------
__global__ __launch_bounds__(64) void scan_kernel(
    const float* __restrict__ carry, const float* __restrict__ Wh,
    float* __restrict__ out, float* __restrict__ hprev)
{
    const int b = blockIdx.x;
    const int j = threadIdx.x;
    float wcol[64];
#pragma unroll
    for (int m = 0; m < 64; ++m) wcol[m] = Wh[m * 64 + j];

    __shared__ __align__(16) float sh[64];
    float a_prev = carry[b * 64 + j];
    sh[j] = a_prev;
    float* ub = out + OFF_OUT + b * 8192;          // u in, a out (in place)
    float* hb = hprev + b * 8192;
    float u0 = ub[j];
    float u1 = ub[64 + j];
    const f32x4* shv = reinterpret_cast<const f32x4*>(sh);
    float a = 0.0f;

    for (int t = 0; t < 128; ++t) {
        hb[t * 64 + j] = a_prev;                   // h entering step t
        const float pre = u0;
        u0 = u1;
        if (t + 2 < 128) u1 = ub[(t + 2) * 64 + j];
        float s0 = 0.f, s1 = 0.f, s2 = 0.f, s3 = 0.f;
#pragma unroll
        for (int mm = 0; mm < 16; ++mm) {
            const f32x4 hv = shv[mm];              // lane-uniform broadcast
            s0 = fmaf(hv.x, wcol[mm * 4 + 0], s0);
            s1 = fmaf(hv.y, wcol[mm * 4 + 1], s1);
            s2 = fmaf(hv.z, wcol[mm * 4 + 2], s2);
            s3 = fmaf(hv.w, wcol[mm * 4 + 3], s3);
        }
        a = tanh_fast(pre + (s0 + s1) + (s2 + s3));
        ub[t * 64 + j] = a;
        sh[j] = a;                                 // same-wave LDS exchange
        a_prev = a;
    }
    out[b * 64 + j] = a;                           // final carry
}

// ---------------------------------------------------------------------------
// Kernel 3: single-touch SWEEP fill. Grid-stride over float4 units of the
// whole Jacobian span -> at any instant the device writes one contiguous
// ~8MB advancing window (memset-like DRAM pattern). No LDS, no barriers;
// reads are 1-2 L2-hot dwords per unit; NT full-line stores.
// ---------------------------------------------------------------------------
__global__ __launch_bounds__(256) void fill_sweep(
    const float* __restrict__ x, float* __restrict__ out,
    const float* __restrict__ whT, const float* __restrict__ hprev)
{
    const float* __restrict__ outh = out + OFF_OUT;
    const f32x4* __restrict__ whT4 = reinterpret_cast<const f32x4*>(whT);
    f32x4* __restrict__ o4 = reinterpret_cast<f32x4*>(out);
    const unsigned stride = gridDim.x * blockDim.x;

#pragma unroll 2
    for (unsigned v = JWI4 + blockIdx.x * blockDim.x + threadIdx.x;
         v < END4; v += stride) {
        f32x4 r;
        if (v < JWH4) {
            // J_Wi[b,t,j,i,k]: row = (bt*64+j)*32+i, diag at k=j
            const unsigned u = v - JWI4;
            const unsigned k4 = u & 15u;
            const unsigned row = u >> 4;
            const unsigned i = row & 31u;
            const unsigned jj = (row >> 5) & 63u;
            const unsigned bt = row >> 11;
            const float a = outh[bt * 64u + jj];
            const float val = (1.0f - a * a) * x[bt * 32u + i];
            const unsigned d = jj - k4 * 4u;       // wraps unless diag here
            r.x = (d == 0u) ? val : 0.f; r.y = (d == 1u) ? val : 0.f;
            r.z = (d == 2u) ? val : 0.f; r.w = (d == 3u) ? val : 0.f;
        } else if (v < JB4) {
            // J_Wh[b,t,j,m,k]: row = (bt*64+j)*64+m, diag at k=j
            const unsigned u = v - JWH4;
            const unsigned k4 = u & 15u;
            const unsigned row = u >> 4;
            const unsigned m = row & 63u;
            const unsigned jj = (row >> 6) & 63u;
            const unsigned bt = row >> 12;
            const float a = outh[bt * 64u + jj];
            const float val = (1.0f - a * a) * hprev[bt * 64u + m];
            const unsigned d = jj - k4 * 4u;
            r.x = (d == 0u) ? val : 0.f; r.y = (d == 1u) ? val : 0.f;
            r.z = (d == 2u) ? val : 0.f; r.w = (d == 3u) ? val : 0.f;
        } else if (v < JH4) {
            // J_b[b,t,j,k]: row = bt*64+j, diag at k=j
            const unsigned u = v - JB4;
            const unsigned k4 = u & 15u;
            const unsigned row = u >> 4;
            const unsigned jj = row & 63u;
            const float a = outh[row];
            const float g = 1.0f - a * a;
            const unsigned d = jj - k4 * 4u;
            r.x = (d == 0u) ? g : 0.f; r.y = (d == 1u) ? g : 0.f;
            r.z = (d == 2u) ? g : 0.f; r.w = (d == 3u) ? g : 0.f;
        } else {
            // J_h[b,t,j,c,m]: row = (bt*64+j)*4+c, dense when c==b
            const unsigned u = v - JH4;
            const unsigned k4 = u & 15u;
            const unsigned row = u >> 4;
            const unsigned c = row & 3u;
            const unsigned jj = (row >> 2) & 63u;
            const unsigned bt = row >> 8;
            const unsigned b = bt >> 7;
            const float a = outh[bt * 64u + jj];
            const float g = 1.0f - a * a;
            const f32x4 w4 = whT4[jj * 16u + k4];  // Wh[m0..m0+3][jj]
            const bool on = (c == b);
            r.x = on ? g * w4.x : 0.f; r.y = on ? g * w4.y : 0.f;
            r.z = on ? g * w4.z : 0.f; r.w = on ? g * w4.w : 0.f;
        }
        __builtin_nontemporal_store(r, o4 + v);
    }
}

extern "C" void kernel_launch(void* const* d_in, const int* in_sizes, int n_in,
                              void* d_out, int out_size, void* d_ws, size_t ws_size,
                              hipStream_t stream) {
    const float* carry = (const float*)d_in[0];
    const float* x     = (const float*)d_in[1];
    const float* Wi    = (const float*)d_in[2];
    const float* Wh    = (const float*)d_in[3];
    const float* bias  = (const float*)d_in[4];
    float* out = (float*)d_out;
    float* whT   = (float*)d_ws;                   // 4096 floats (16 KB)
    float* hprev = whT + 4096;                     // 32768 floats (128 KB)

    whT_kernel <<<16, 256, 0, stream>>>(Wh, whT);
    xwi_kernel <<<128, 256, 0, stream>>>(x, Wi, bias, out);
    scan_kernel<<<4, 64, 0, stream>>>(carry, Wh, out, hprev);
    fill_sweep <<<2048, 256, 0, stream>>>(x, out, whT, hprev);
}

// Round 9
// 203.359 us; speedup vs baseline: 6.5453x; 1.0607x over previous
//
#include <hip/hip_runtime.h>
#include <math.h>

// Problem dims: B=4, T=128, I=32, H=64 (compile-time)
// d_out float layout (reference return order):
// final_carry (4,64) | out (4,128,64) | J_Wi (4,128,64,32,64) | J_Wh (4,128,64,64,64)
// | J_b (4,128,64,64) | J_h (4,128,64,4,64)
#define OFF_OUT   256u
#define OFF_JWI   33024u
#define OFF_JWH   67141888u
#define OFF_JB    201359616u
#define OFF_JH    203456768u

typedef float f32x4 __attribute__((ext_vector_type(4)));

static __device__ __forceinline__ float tanh_fast(float x) {
    // tanh(x) = 1 - 2/(e^{2x}+1); exact limits, ~1e-6 rel error
    float t = __expf(2.0f * x);
    return 1.0f - 2.0f / (t + 1.0f);
}

// ---------------------------------------------------------------------------
// Kernel 1: u[bt,j] = b[j] + sum_i x[bt,i]*Wi[i,j]  (staged at start of J_b
// region; diag pass overwrites it afterwards). 128 blocks x 256 threads.
// ---------------------------------------------------------------------------
__global__ __launch_bounds__(256) void xwi_kernel(
    const float* __restrict__ x, const float* __restrict__ Wi,
    const float* __restrict__ bias, float* __restrict__ u)
{
    const int tid = threadIdx.x;
    const int row = blockIdx.x * 4 + (tid >> 6);   // bt in [0,512)
    const int j = tid & 63;
    const float* xr = x + row * 32;
    float acc = bias[j];
#pragma unroll
    for (int i = 0; i < 32; ++i) acc = fmaf(xr[i], Wi[i * 64 + j], acc);
    u[row * 64 + j] = acc;
}

// ---------------------------------------------------------------------------
// Kernel 2: block 0 = sequential scan (wave w = batch w, barrier-free: each
// wave touches only its own sh slice, same-wave LDS ordering is enough).
// Blocks 1..G-1 = zero-fill of all structurally-zero half-lines (PLAIN
// stores this round — NT was the single change vs the 184us R4 baseline):
//   unit < 131072:  J_Wi non-diag 128B half-lines (unit = 8 rows)
//   unit < 393216:  J_Wh non-diag 128B half-lines (unit = 8 rows)
//   else         :  J_h flat memset (unit = 256 floats)
// ---------------------------------------------------------------------------
__global__ __launch_bounds__(256) void scan_zero_kernel(
    const float* __restrict__ carry, const float* __restrict__ u,
    const float* __restrict__ Wh, float* __restrict__ out)
{
    const int tid = threadIdx.x;
    if (blockIdx.x == 0) {
        const int w = tid >> 6, j = tid & 63;
        float wcol[64];
#pragma unroll
        for (int m = 0; m < 64; ++m) wcol[m] = Wh[m * 64 + j];
        __shared__ __align__(16) float sh[256];
        sh[tid] = carry[tid];
        const float* ub = u + w * 8192;
        float* ob = out + OFF_OUT + w * 8192;
        const f32x4* shv = reinterpret_cast<const f32x4*>(sh + w * 64);
        float unext = ub[j];
        float a = 0.0f;
        for (int t = 0; t < 128; ++t) {
            const float pre = unext;
            if (t < 127) unext = ub[(t + 1) * 64 + j];
            float a0 = 0.f, a1 = 0.f, a2 = 0.f, a3 = 0.f;
#pragma unroll
            for (int mm = 0; mm < 16; ++mm) {
                const f32x4 hv = shv[mm];           // lane-uniform 16B read
                a0 = fmaf(hv.x, wcol[mm * 4 + 0], a0);
                a1 = fmaf(hv.y, wcol[mm * 4 + 1], a1);
                a2 = fmaf(hv.z, wcol[mm * 4 + 2], a2);
                a3 = fmaf(hv.w, wcol[mm * 4 + 3], a3);
            }
            a = tanh_fast(pre + (a0 + a1) + (a2 + a3));
            ob[t * 64 + j] = a;
            sh[tid] = a;                             // next iter reads it
        }
        out[tid] = a;                                // final carry
    } else {
        const unsigned NW = (gridDim.x - 1u) * 4u;
        const unsigned l = tid & 63u;
        const f32x4 z = {0.f, 0.f, 0.f, 0.f};
        for (unsigned uu = (blockIdx.x - 1u) * 4u + (tid >> 6);
             uu < 425984u; uu += NW) {
            unsigned addr;
            if (uu < 131072u) {
                const unsigned r0 = uu * 8u;                 // J_Wi row
                const unsigned j = (r0 >> 5) & 63u;          // uniform over 8 rows
                addr = OFF_JWI + r0 * 64u + ((j < 32u) ? 32u : 0u)
                     + (l >> 3) * 64u + (l & 7u) * 4u;
            } else if (uu < 393216u) {
                const unsigned r0 = (uu - 131072u) * 8u;     // J_Wh row
                const unsigned j = (r0 >> 6) & 63u;
                addr = OFF_JWH + r0 * 64u + ((j < 32u) ? 32u : 0u)
                     + (l >> 3) * 64u + (l & 7u) * 4u;
            } else {
                addr = OFF_JH + (uu - 393216u) * 256u + l * 4u;
            }
            *reinterpret_cast<f32x4*>(out + addr) = z;
        }
    }
}

// ---------------------------------------------------------------------------
// Kernel 3: data-dependent fill (diag half-lines + dense J_h rows), PLAIN
// stores.
//   unit < 131072:  J_Wi diag halves   (unit = 8 rows, 1 f32x4/lane)
//   unit < 393216:  J_Wh diag halves   (unit = 8 rows)
//   unit < 401408:  J_b full rows      (unit = 4 rows of 64 floats)
//   else         :  J_h c==b rows      (unit = 4 (bt,j) rows of 64 floats)
// ---------------------------------------------------------------------------
__global__ __launch_bounds__(256) void diag_fill_kernel(
    const float* __restrict__ carry, const float* __restrict__ x,
    const float* __restrict__ Wh, float* __restrict__ out)
{
    const int tid = threadIdx.x;
    const unsigned NW = gridDim.x * 4u;
    const unsigned l = tid & 63u;
    const float* __restrict__ outh = out + OFF_OUT;

    for (unsigned uu = blockIdx.x * 4u + (tid >> 6); uu < 409600u; uu += NW) {
        unsigned addr;
        f32x4 r = {0.f, 0.f, 0.f, 0.f};
        if (uu < 131072u) {
            const unsigned r0 = uu * 8u;
            const unsigned bt = r0 >> 11;
            const unsigned j = (r0 >> 5) & 63u;
            const float a = outh[bt * 64u + j];          // wave-uniform
            const float g = 1.0f - a * a;
            const unsigned i = (r0 + (l >> 3)) & 31u;
            const float v = g * x[bt * 32u + i];
            const unsigned d = (j & 31u) - (l & 7u) * 4u; // wraps if diag elsewhere
            r.x = (d == 0u) ? v : 0.f; r.y = (d == 1u) ? v : 0.f;
            r.z = (d == 2u) ? v : 0.f; r.w = (d == 3u) ? v : 0.f;
            addr = OFF_JWI + r0 * 64u + ((j < 32u) ? 0u : 32u)
                 + (l >> 3) * 64u + (l & 7u) * 4u;
        } else if (uu < 393216u) {
            const unsigned r0 = (uu - 131072u) * 8u;
            const unsigned bt = r0 >> 12;
            const unsigned j = (r0 >> 6) & 63u;
            const unsigned t = bt & 127u, b = bt >> 7;
            const float a = outh[bt * 64u + j];
            const float g = 1.0f - a * a;
            const unsigned m = (r0 + (l >> 3)) & 63u;
            const float hv = (t == 0u) ? carry[b * 64u + m]
                                       : outh[(bt - 1u) * 64u + m];
            const float v = g * hv;
            const unsigned d = (j & 31u) - (l & 7u) * 4u;
            r.x = (d == 0u) ? v : 0.f; r.y = (d == 1u) ? v : 0.f;
            r.z = (d == 2u) ? v : 0.f; r.w = (d == 3u) ? v : 0.f;
            addr = OFF_JWH + r0 * 64u + ((j < 32u) ? 0u : 32u)
                 + (l >> 3) * 64u + (l & 7u) * 4u;
        } else if (uu < 401408u) {
            const unsigned p = (uu - 393216u) * 4u + (l >> 4);  // row = bt*64+j
            const unsigned j = p & 63u;
            const float a = outh[p];
            const float g = 1.0f - a * a;
            const unsigned d = j - (l & 15u) * 4u;
            r.x = (d == 0u) ? g : 0.f; r.y = (d == 1u) ? g : 0.f;
            r.z = (d == 2u) ? g : 0.f; r.w = (d == 3u) ? g : 0.f;
            addr = OFF_JB + p * 64u + (l & 15u) * 4u;
        } else {
            const unsigned p = (uu - 401408u) * 4u + (l >> 4);  // bt*64+j
            const unsigned bt = p >> 6, j = p & 63u, b = bt >> 7;
            const float a = outh[p];
            const float g = 1.0f - a * a;
            const unsigned k0 = (l & 15u) * 4u;
            r.x = g * Wh[(k0 + 0u) * 64u + j];
            r.y = g * Wh[(k0 + 1u) * 64u + j];
            r.z = g * Wh[(k0 + 2u) * 64u + j];
            r.w = g * Wh[(k0 + 3u) * 64u + j];
            addr = OFF_JH + p * 256u + b * 64u + k0;
        }
        *reinterpret_cast<f32x4*>(out + addr) = r;
    }
}

extern "C" void kernel_launch(void* const* d_in, const int* in_sizes, int n_in,
                              void* d_out, int out_size, void* d_ws, size_t ws_size,
                              hipStream_t stream) {
    const float* carry = (const float*)d_in[0];
    const float* x     = (const float*)d_in[1];
    const float* Wi    = (const float*)d_in[2];
    const float* Wh    = (const float*)d_in[3];
    const float* bias  = (const float*)d_in[4];
    float* out = (float*)d_out;
    float* u = out + OFF_JB;   // staging; overwritten by diag_fill_kernel

    xwi_kernel      <<<128, 256, 0, stream>>>(x, Wi, bias, u);
    scan_zero_kernel<<<2048, 256, 0, stream>>>(carry, u, Wh, out);
    diag_fill_kernel<<<2048, 256, 0, stream>>>(carry, x, Wh, out);
}